// Round 6
// baseline (1631.820 us; speedup 1.0000x reference)
//
#include <hip/hip_runtime.h>
#include <hip/hip_bf16.h>

#define AS1 __attribute__((address_space(1)))
#define AS3 __attribute__((address_space(3)))

typedef __attribute__((ext_vector_type(8))) short bf16x8;
typedef __attribute__((ext_vector_type(4))) float f32x4;

#define CSTRIDE 9216   // coeff row stride = O*(D+1)
#define KT2 8192       // GEMM K: polys T_1..T_8, k = (d-1)*1024 + i
#define NOUT 1024
#define HALF_ELEMS (8192u * 1024u)   // one partial buffer (fp32 elems)

__device__ __forceinline__ void gll16(const void* g, void* l) {
    __builtin_amdgcn_global_load_lds((const AS1 void*)g, (AS3 void*)l, 16, 0, 0);
}
static __device__ __forceinline__ unsigned short f2bf(float f) {
    union { __hip_bfloat16 h; unsigned short u; } cv;
    cv.h = __float2bfloat16(f);
    return cv.u;
}
static __device__ __forceinline__ float bf2f(unsigned short u) {
    union { float f; unsigned v; } c; c.v = (unsigned)u << 16; return c.f;
}
static __device__ __forceinline__ float fast_tanhf(float v) {
    float e = __expf(2.0f * v);
    return 1.0f - 2.0f / (e + 1.0f);
}

// ---------------------------------------------------------------------------
// Prep: cc (I=1024, O=1024, 9) f32 -> Wt[n][k] bf16, k=(d-1)*1024+i (d=1..8),
// PRE-SWIZZLED within each 64-chunk (Wt[n][e] = W[n][e ^ ((n&7)<<3)]) so a
// linear global_load_lds lands XOR-swizzled in LDS. Plus bias[o] = sum_i
// cc[i][o][0] (the T_0 term) via fp32 atomics.  (proven R4/R5)
// ---------------------------------------------------------------------------
__global__ void __launch_bounds__(256) prep_kernel(const float* __restrict__ cc,
                                                   unsigned short* __restrict__ Wt,
                                                   float* __restrict__ bias) {
    __shared__ unsigned short T[288 * 68];  // [f = nl*9 + d][il], pad 68
    const int t  = threadIdx.x;
    const int n0 = (blockIdx.x & 31) * 32;
    const int i0 = (blockIdx.x >> 5) * 64;

    for (int il = 0; il < 64; ++il) {
        const float* src = cc + (size_t)(i0 + il) * CSTRIDE + (size_t)n0 * 9;
        for (int f = t; f < 288; f += 256)
            T[f * 68 + il] = f2bf(src[f]);
    }
    __syncthreads();

#pragma unroll
    for (int it = 0; it < 16; ++it) {
        const int chunk = it * 16 + (t >> 4);
        const int nl = chunk >> 3;
        const int dd = chunk & 7;
        const int n  = n0 + nl;
        const int e0 = (t & 15) * 4;
        const int isrc = e0 ^ ((n & 7) << 3);
        ushort4 v = *(const ushort4*)&T[(nl * 9 + dd + 1) * 68 + isrc];
        *(ushort4*)(Wt + (size_t)n * KT2 + dd * 1024 + i0 + e0) = v;
    }

    if (t < 32) {
        float s = 0.f;
#pragma unroll 8
        for (int il = 0; il < 64; ++il) s += bf2f(T[(t * 9) * 68 + il]);
        atomicAdd(&bias[n0 + t], s);
    }
}

// ---------------------------------------------------------------------------
// Fused GEMM, split-K templated.
// SPLIT=true : grid 1024, each block does one K-half (ic 0-7 or 8-15),
//              4 blocks/CU (the R5-proven occupancy mechanism) at R1's
//              staging cost (128x128 tile), writes fp32 partials to ws.
// SPLIT=false: grid 512, full K, writes out + bias directly (fallback).
// Schedule: R1's proven 2-barrier __syncthreads form. No vmcnt games.
// ---------------------------------------------------------------------------
template <bool SPLIT>
__global__ void __launch_bounds__(256, SPLIT ? 4 : 2)
cheby_gemm(const float* __restrict__ x, const unsigned short* __restrict__ Wt,
           const float* __restrict__ bias, float* __restrict__ outp) {
    __shared__ unsigned short Asub[128 * 64];   // 16 KB, [row][kc] swizzled
    __shared__ unsigned short Bsub[128 * 64];   // 16 KB, [n][kc] swizzled

    const int id   = blockIdx.x;
    const int bcol = (id & 7) * 128;          // col strip fixed per XCD
    const int brow = ((id >> 3) & 63) * 128;
    const int kh   = SPLIT ? (id >> 9) : 0;   // k-half
    const int ic0  = kh * 8;
    const int nic  = SPLIT ? 8 : 16;

    const int t    = threadIdx.x;
    const int lane = t & 63;
    const int w    = t >> 6;
    const int wr   = (w >> 1) * 64;
    const int wc   = (w & 1) * 64;
    const int l15  = lane & 15;
    const int lhi  = lane >> 4;

    const int gi0 = (t & 15) * 4;   // gen: i-quad
    const int gr  = t >> 4;         // gen: base row, covers gr+16p
    const int bn_loc = t >> 3;      // B staging row-in-chunk
    const int bpos   = (t & 7) * 8; // B staging elem offset (16 B)

    unsigned awoff[8];
#pragma unroll
    for (int p = 0; p < 8; ++p) {
        const int r = gr + 16 * p;
        awoff[p] = r * 128 + ((gi0 * 2) ^ ((r & 7) << 4));
    }

    f32x4 acc[4][4] = {};
    float x2[8][4], Tp[8][4], Tpp[8][4];

#pragma unroll 1
    for (int ici = 0; ici < nic; ++ici) {
        const int ic = ic0 + ici;
        float4 xt[8];
#pragma unroll
        for (int p = 0; p < 8; ++p)
            xt[p] = *(const float4*)(x + (size_t)(brow + gr + 16 * p) * 1024
                                     + ic * 64 + gi0);

#pragma unroll
        for (int dd = 0; dd < 8; ++dd) {
            __syncthreads();   // MFMA(s-1) reads done before overwriting LDS

            // stage B(s): 4 chunks x (64 lanes x 16 B), linear dest per wave
            const int kb = dd * 1024 + ic * 64;
#pragma unroll
            for (int c = 0; c < 4; ++c)
                gll16(Wt + (size_t)(bcol + c * 32 + bn_loc) * KT2 + kb + bpos,
                      (char*)Bsub + c * 4096 + w * 1024);

            // generate A(s) = T_{dd+1} tile (fp32 recurrence, bf16 pack)
            if (dd == 0) {
#pragma unroll
                for (int p = 0; p < 8; ++p) {
                    ushort4 pk; unsigned short* pks = (unsigned short*)&pk;
#pragma unroll
                    for (int j = 0; j < 4; ++j) {
                        x2[p][j] = 2.0f * fast_tanhf((&xt[p].x)[j]);
                        const float c = 0.5f * x2[p][j];
                        Tp[p][j] = c; Tpp[p][j] = 1.0f;
                        pks[j] = f2bf(c);
                    }
                    *(ushort4*)((char*)Asub + awoff[p]) = pk;
                }
            } else {
#pragma unroll
                for (int p = 0; p < 8; ++p) {
                    ushort4 pk; unsigned short* pks = (unsigned short*)&pk;
#pragma unroll
                    for (int j = 0; j < 4; ++j) {
                        const float c = __builtin_fmaf(x2[p][j], Tp[p][j], -Tpp[p][j]);
                        Tpp[p][j] = Tp[p][j]; Tp[p][j] = c;
                        pks[j] = f2bf(c);
                    }
                    *(ushort4*)((char*)Asub + awoff[p]) = pk;
                }
            }

            __syncthreads();   // full drain: A written, B landed

            // MFMA phase: BK=64 -> 2 k-steps of 32
#pragma unroll
            for (int ks = 0; ks < 2; ++ks) {
                bf16x8 af[4], bfr[4];
#pragma unroll
                for (int mf = 0; mf < 4; ++mf) {
                    const int row = wr + mf * 16 + l15;
                    af[mf] = *(const bf16x8*)((const char*)Asub + row * 128 +
                              ((ks * 64 + lhi * 16) ^ ((row & 7) << 4)));
                }
#pragma unroll
                for (int nf = 0; nf < 4; ++nf) {
                    const int n = wc + nf * 16 + l15;
                    bfr[nf] = *(const bf16x8*)((const char*)Bsub + n * 128 +
                              ((ks * 64 + lhi * 16) ^ ((n & 7) << 4)));
                }
#pragma unroll
                for (int mf = 0; mf < 4; ++mf)
#pragma unroll
                    for (int nf = 0; nf < 4; ++nf)
                        acc[mf][nf] = __builtin_amdgcn_mfma_f32_16x16x32_bf16(
                            af[mf], bfr[nf], acc[mf][nf], 0, 0, 0);
            }
        }
    }

    // epilogue: C/D layout col = lane&15, row = (lane>>4)*4 + reg
    float* dst = SPLIT ? (outp + (size_t)kh * HALF_ELEMS) : outp;
    float bv[4];
    if (!SPLIT) {
#pragma unroll
        for (int nf = 0; nf < 4; ++nf) bv[nf] = bias[bcol + wc + nf * 16 + l15];
    }
#pragma unroll
    for (int mf = 0; mf < 4; ++mf)
#pragma unroll
        for (int nf = 0; nf < 4; ++nf)
#pragma unroll
            for (int ri = 0; ri < 4; ++ri) {
                const int orow = brow + wr + mf * 16 + lhi * 4 + ri;
                const int ocol = bcol + wc + nf * 16 + l15;
                const float v = SPLIT ? acc[mf][nf][ri] : (acc[mf][nf][ri] + bv[nf]);
                dst[(size_t)orow * NOUT + ocol] = v;
            }
}

// ---------------------------------------------------------------------------
// Reduce: out = p0 + p1 + bias (fp32, float4, grid-stride)
// ---------------------------------------------------------------------------
__global__ void __launch_bounds__(256) reduce_kernel(const float* __restrict__ partial,
                                                     const float* __restrict__ bias,
                                                     float* __restrict__ out) {
    const unsigned n4 = HALF_ELEMS / 4;
    const float4* p0 = (const float4*)partial;
    const float4* p1 = (const float4*)(partial + HALF_ELEMS);
    const float4* bz = (const float4*)bias;
    float4* o4 = (float4*)out;
    for (unsigned idx = blockIdx.x * 256u + threadIdx.x; idx < n4;
         idx += gridDim.x * 256u) {
        const float4 a = p0[idx];
        const float4 b = p1[idx];
        const float4 bv = bz[idx & 255u];   // 256 float4 per row of 1024
        float4 r;
        r.x = a.x + b.x + bv.x;
        r.y = a.y + b.y + bv.y;
        r.z = a.z + b.z + bv.z;
        r.w = a.w + b.w + bv.w;
        o4[idx] = r;
    }
}

// ---------------------------------------------------------------------------
// Fallback (ws far too small): correct but slow fp32 path.
// ---------------------------------------------------------------------------
__global__ void __launch_bounds__(256) naive_kernel(const float* __restrict__ x,
                                                    const float* __restrict__ cc,
                                                    float* __restrict__ out) {
    __shared__ float xs[1024];
    const int b = blockIdx.x;
    const int t = threadIdx.x;
#pragma unroll
    for (int j = 0; j < 4; ++j)
        xs[t * 4 + j] = fast_tanhf(x[(size_t)b * 1024 + t * 4 + j]);
    __syncthreads();

    const int o = t * 4;
    float a0 = 0.f, a1 = 0.f, a2 = 0.f, a3 = 0.f;
    for (int i = 0; i < 1024; ++i) {
        const float* cp = cc + (size_t)i * CSTRIDE + (size_t)o * 9;
        const float xv = xs[i];
        float tpp = 1.0f, tp = xv;
        a0 += cp[0];  a1 += cp[9];  a2 += cp[18];  a3 += cp[27];
        a0 += xv * cp[1]; a1 += xv * cp[10]; a2 += xv * cp[19]; a3 += xv * cp[28];
#pragma unroll
        for (int d = 2; d <= 8; ++d) {
            const float cur = 2.0f * xv * tp - tpp;
            tpp = tp; tp = cur;
            a0 += cur * cp[d];      a1 += cur * cp[9 + d];
            a2 += cur * cp[18 + d]; a3 += cur * cp[27 + d];
        }
    }
    float* op = out + (size_t)b * NOUT + o;
    op[0] = a0; op[1] = a1; op[2] = a2; op[3] = a3;
}

extern "C" void kernel_launch(void* const* d_in, const int* in_sizes, int n_in,
                              void* d_out, int out_size, void* d_ws, size_t ws_size,
                              hipStream_t stream) {
    const float* x  = (const float*)d_in[0];
    const float* cc = (const float*)d_in[1];
    float* out = (float*)d_out;

    const size_t wt_bytes   = (size_t)KT2 * 1024 * sizeof(unsigned short); // 16 MiB
    const size_t part_bytes = (size_t)2 * HALF_ELEMS * sizeof(float);      // 64 MiB
    const size_t need_split  = wt_bytes + part_bytes + 1024 * sizeof(float);
    const size_t need_single = wt_bytes + 1024 * sizeof(float);

    if (ws_size >= need_split) {
        unsigned short* Wt = (unsigned short*)d_ws;
        float* partial = (float*)((char*)d_ws + wt_bytes);
        float* bias    = (float*)((char*)d_ws + wt_bytes + part_bytes);
        hipMemsetAsync(bias, 0, 1024 * sizeof(float), stream);
        prep_kernel<<<512, 256, 0, stream>>>(cc, Wt, bias);
        cheby_gemm<true><<<1024, 256, 0, stream>>>(x, Wt, bias, partial);
        reduce_kernel<<<2048, 256, 0, stream>>>(partial, bias, out);
    } else if (ws_size >= need_single) {
        unsigned short* Wt = (unsigned short*)d_ws;
        float* bias = (float*)((char*)d_ws + wt_bytes);
        hipMemsetAsync(bias, 0, 1024 * sizeof(float), stream);
        prep_kernel<<<512, 256, 0, stream>>>(cc, Wt, bias);
        cheby_gemm<false><<<512, 256, 0, stream>>>(x, Wt, bias, out);
    } else {
        naive_kernel<<<8192, 256, 0, stream>>>(x, cc, out);
    }
}

// Round 7
// 239.962 us; speedup vs baseline: 6.8003x; 6.8003x over previous
//
#include <hip/hip_runtime.h>
#include <hip/hip_bf16.h>

#define AS1 __attribute__((address_space(1)))
#define AS3 __attribute__((address_space(3)))

typedef __attribute__((ext_vector_type(8))) short bf16x8;
typedef __attribute__((ext_vector_type(4))) float f32x4;

#define CSTRIDE 9216   // coeff row stride = O*(D+1)
#define KT2 8192       // GEMM K: polys T_1..T_8, k = (d-1)*1024 + i
#define NOUT 1024

__device__ __forceinline__ void gll16(const void* g, void* l) {
    __builtin_amdgcn_global_load_lds((const AS1 void*)g, (AS3 void*)l, 16, 0, 0);
}
static __device__ __forceinline__ unsigned short f2bf(float f) {
    union { __hip_bfloat16 h; unsigned short u; } cv;
    cv.h = __float2bfloat16(f);
    return cv.u;
}
static __device__ __forceinline__ float bf2f(unsigned short u) {
    union { float f; unsigned v; } c; c.v = (unsigned)u << 16; return c.f;
}
static __device__ __forceinline__ float fast_tanhf(float v) {
    float e = __expf(2.0f * v);
    return 1.0f - 2.0f / (e + 1.0f);
}

// ---------------------------------------------------------------------------
// Prep: cc (I=1024, O=1024, 9) f32 -> Wt[n][k] bf16, k=(d-1)*1024+i (d=1..8),
// PRE-SWIZZLED within each 64-chunk (Wt[n][e] = W[n][e ^ ((n&7)<<3)]) so a
// linear global_load_lds lands XOR-swizzled in LDS. Plus bias[o] = sum_i
// cc[i][o][0] (the T_0 term) via fp32 atomics.  (proven R4-R6)
// ---------------------------------------------------------------------------
__global__ void __launch_bounds__(256) prep_kernel(const float* __restrict__ cc,
                                                   unsigned short* __restrict__ Wt,
                                                   float* __restrict__ bias) {
    __shared__ unsigned short T[288 * 68];  // [f = nl*9 + d][il], pad 68
    const int t  = threadIdx.x;
    const int n0 = (blockIdx.x & 31) * 32;
    const int i0 = (blockIdx.x >> 5) * 64;

    for (int il = 0; il < 64; ++il) {
        const float* src = cc + (size_t)(i0 + il) * CSTRIDE + (size_t)n0 * 9;
        for (int f = t; f < 288; f += 256)
            T[f * 68 + il] = f2bf(src[f]);
    }
    __syncthreads();

#pragma unroll
    for (int it = 0; it < 16; ++it) {
        const int chunk = it * 16 + (t >> 4);
        const int nl = chunk >> 3;
        const int dd = chunk & 7;
        const int n  = n0 + nl;
        const int e0 = (t & 15) * 4;
        const int isrc = e0 ^ ((n & 7) << 3);
        ushort4 v = *(const ushort4*)&T[(nl * 9 + dd + 1) * 68 + isrc];
        *(ushort4*)(Wt + (size_t)n * KT2 + dd * 1024 + i0 + e0) = v;
    }

    if (t < 32) {
        float s = 0.f;
#pragma unroll 8
        for (int il = 0; il < 64; ++il) s += bf2f(T[(t * 9) * 68 + il]);
        atomicAdd(&bias[n0 + t], s);
    }
}

// ---------------------------------------------------------------------------
// Fused GEMM: out[8192][1024] = Cheby_{1..8}(tanh(x)) @ Wt^T + bias
// 128x128 tile, **512 threads = 8 waves** (2 row-bands x 4 col-bands; wave
// tile 64x32). Rationale (R5/R6 post-mortems): 16 waves/CU (2 blocks/CU,
// __launch_bounds__(512,4)) gives R5's proven cross-block overlap, while
// the 8-wave split halves per-thread register demand vs R6's spill disaster:
// gen state 48 fp32 + acc 32 + frags fits the 128-reg/wave cap.
// Schedule: R1's proven 2-barrier __syncthreads form. K=8192, T_0 -> bias.
// ---------------------------------------------------------------------------
__global__ void __launch_bounds__(512, 4)
cheby_gemm(const float* __restrict__ x, const unsigned short* __restrict__ Wt,
           const float* __restrict__ bias, float* __restrict__ out) {
    __shared__ unsigned short Asub[128 * 64];   // 16 KB, [row][kc] swizzled
    __shared__ unsigned short Bsub[128 * 64];   // 16 KB, [n][kc] swizzled

    const int id   = blockIdx.x;       // 512 blocks
    const int bcol = (id & 7) * 128;   // col strip fixed per XCD
    const int brow = (id >> 3) * 128;
    const int t    = threadIdx.x;
    const int lane = t & 63;
    const int w    = t >> 6;           // 0..7
    const int wr   = (w >> 2) * 64;    // wave row offset (2 row-bands)
    const int wc   = (w & 3) * 32;     // wave col offset (4 col-bands)
    const int l15  = lane & 15;
    const int lhi  = lane >> 4;

    const int gi0 = (t & 15) * 4;   // gen: i-quad
    const int gr  = t >> 4;         // gen: base row 0..31, covers gr+32p, p<4
    const int bl3 = (lane >> 3);    // B staging: row-in-8
    const int bp8 = (lane & 7) * 8; // B staging: elem offset (16 B)

    unsigned awoff[4];
#pragma unroll
    for (int p = 0; p < 4; ++p) {
        const int r = gr + 32 * p;
        awoff[p] = r * 128 + ((gi0 * 2) ^ ((r & 7) << 4));
    }

    f32x4 acc[4][2] = {};
    float x2[4][4], Tp[4][4], Tpp[4][4];

#pragma unroll 1
    for (int ic = 0; ic < 16; ++ic) {
#pragma unroll
        for (int dd = 0; dd < 8; ++dd) {
            __syncthreads();   // MFMA(s-1) reads done before overwriting LDS

            // stage B(s): 16 KB; 8 waves x 2 calls x (64 lanes x 16 B).
            // Wave call c covers rows w*16 + c*8 .. +7 (linear LDS dest).
            const int kb = dd * 1024 + ic * 64;
#pragma unroll
            for (int c = 0; c < 2; ++c) {
                const int n_loc = w * 16 + c * 8 + bl3;
                gll16(Wt + (size_t)(bcol + n_loc) * KT2 + kb + bp8,
                      (char*)Bsub + (w * 16 + c * 8) * 128);
            }

            // generate A(s) = T_{dd+1} tile (fp32 recurrence, bf16 pack)
            if (dd == 0) {
#pragma unroll
                for (int p = 0; p < 4; ++p) {
                    const float4 v = *(const float4*)(x +
                        (size_t)(brow + gr + 32 * p) * 1024 + ic * 64 + gi0);
                    ushort4 pk; unsigned short* pks = (unsigned short*)&pk;
#pragma unroll
                    for (int j = 0; j < 4; ++j) {
                        x2[p][j] = 2.0f * fast_tanhf((&v.x)[j]);
                        const float c = 0.5f * x2[p][j];
                        Tp[p][j] = c; Tpp[p][j] = 1.0f;
                        pks[j] = f2bf(c);
                    }
                    *(ushort4*)((char*)Asub + awoff[p]) = pk;
                }
            } else {
#pragma unroll
                for (int p = 0; p < 4; ++p) {
                    ushort4 pk; unsigned short* pks = (unsigned short*)&pk;
#pragma unroll
                    for (int j = 0; j < 4; ++j) {
                        const float c = __builtin_fmaf(x2[p][j], Tp[p][j], -Tpp[p][j]);
                        Tpp[p][j] = Tp[p][j]; Tp[p][j] = c;
                        pks[j] = f2bf(c);
                    }
                    *(ushort4*)((char*)Asub + awoff[p]) = pk;
                }
            }

            __syncthreads();   // full drain: A written, B landed

            // MFMA phase: BK=64 -> 2 k-steps of 32; wave tile 64x32
#pragma unroll
            for (int ks = 0; ks < 2; ++ks) {
                bf16x8 af[4], bfr[2];
#pragma unroll
                for (int mf = 0; mf < 4; ++mf) {
                    const int row = wr + mf * 16 + l15;
                    af[mf] = *(const bf16x8*)((const char*)Asub + row * 128 +
                              ((ks * 64 + lhi * 16) ^ ((row & 7) << 4)));
                }
#pragma unroll
                for (int nf = 0; nf < 2; ++nf) {
                    const int n = wc + nf * 16 + l15;
                    bfr[nf] = *(const bf16x8*)((const char*)Bsub + n * 128 +
                              ((ks * 64 + lhi * 16) ^ ((n & 7) << 4)));
                }
#pragma unroll
                for (int mf = 0; mf < 4; ++mf)
#pragma unroll
                    for (int nf = 0; nf < 2; ++nf)
                        acc[mf][nf] = __builtin_amdgcn_mfma_f32_16x16x32_bf16(
                            af[mf], bfr[nf], acc[mf][nf], 0, 0, 0);
            }
        }
    }

    // epilogue: C/D layout col = lane&15, row = (lane>>4)*4 + reg; + bias
    float bv[2];
#pragma unroll
    for (int nf = 0; nf < 2; ++nf) bv[nf] = bias[bcol + wc + nf * 16 + l15];
#pragma unroll
    for (int mf = 0; mf < 4; ++mf)
#pragma unroll
        for (int nf = 0; nf < 2; ++nf)
#pragma unroll
            for (int ri = 0; ri < 4; ++ri) {
                const int orow = brow + wr + mf * 16 + lhi * 4 + ri;
                const int ocol = bcol + wc + nf * 16 + l15;
                out[(size_t)orow * NOUT + ocol] = acc[mf][nf][ri] + bv[nf];
            }
}

// ---------------------------------------------------------------------------
// Fallback (ws too small): correct but slow fp32 path.
// ---------------------------------------------------------------------------
__global__ void __launch_bounds__(256) naive_kernel(const float* __restrict__ x,
                                                    const float* __restrict__ cc,
                                                    float* __restrict__ out) {
    __shared__ float xs[1024];
    const int b = blockIdx.x;
    const int t = threadIdx.x;
#pragma unroll
    for (int j = 0; j < 4; ++j)
        xs[t * 4 + j] = fast_tanhf(x[(size_t)b * 1024 + t * 4 + j]);
    __syncthreads();

    const int o = t * 4;
    float a0 = 0.f, a1 = 0.f, a2 = 0.f, a3 = 0.f;
    for (int i = 0; i < 1024; ++i) {
        const float* cp = cc + (size_t)i * CSTRIDE + (size_t)o * 9;
        const float xv = xs[i];
        float tpp = 1.0f, tp = xv;
        a0 += cp[0];  a1 += cp[9];  a2 += cp[18];  a3 += cp[27];
        a0 += xv * cp[1]; a1 += xv * cp[10]; a2 += xv * cp[19]; a3 += xv * cp[28];
#pragma unroll
        for (int d = 2; d <= 8; ++d) {
            const float cur = 2.0f * xv * tp - tpp;
            tpp = tp; tp = cur;
            a0 += cur * cp[d];      a1 += cur * cp[9 + d];
            a2 += cur * cp[18 + d]; a3 += cur * cp[27 + d];
        }
    }
    float* op = out + (size_t)b * NOUT + o;
    op[0] = a0; op[1] = a1; op[2] = a2; op[3] = a3;
}

extern "C" void kernel_launch(void* const* d_in, const int* in_sizes, int n_in,
                              void* d_out, int out_size, void* d_ws, size_t ws_size,
                              hipStream_t stream) {
    const float* x  = (const float*)d_in[0];
    const float* cc = (const float*)d_in[1];
    float* out = (float*)d_out;

    const size_t wt_bytes = (size_t)KT2 * 1024 * sizeof(unsigned short);  // 16 MiB
    const size_t need = wt_bytes + 1024 * sizeof(float);
    if (ws_size >= need) {
        unsigned short* Wt = (unsigned short*)d_ws;
        float* bias = (float*)((char*)d_ws + wt_bytes);
        hipMemsetAsync(bias, 0, 1024 * sizeof(float), stream);
        prep_kernel<<<512, 256, 0, stream>>>(cc, Wt, bias);
        cheby_gemm<<<512, 512, 0, stream>>>(x, Wt, bias, out);
    } else {
        naive_kernel<<<8192, 256, 0, stream>>>(x, cc, out);
    }
}